// Round 6
// baseline (282.909 us; speedup 1.0000x reference)
//
#include <hip/hip_runtime.h>
#include <hip/hip_bf16.h>

typedef __attribute__((ext_vector_type(4))) float float4v;
typedef __attribute__((ext_vector_type(8))) __bf16 bf16x8;
typedef __attribute__((ext_vector_type(4))) unsigned short ushort4v;

#define MFMA16(a, b, c) __builtin_amdgcn_mfma_f32_16x16x32_bf16(a, b, c, 0, 0, 0)

__device__ __forceinline__ unsigned short f2bf(float f) {
    return __builtin_bit_cast(unsigned short, (__bf16)f);
}

// 2^x via native v_exp_f32 (args bounded above by ~13; may be -1e18 -> 0)
__device__ __forceinline__ float fast_exp2(float x) {
#if __has_builtin(__builtin_amdgcn_exp2f)
    return __builtin_amdgcn_exp2f(x);
#else
    return exp2f(x);
#endif
}

// async global->LDS, 16B per lane; lds dest must be wave-uniform base + lane*16
__device__ __forceinline__ void gl_lds16(const unsigned short* g, unsigned short* l) {
    __builtin_amdgcn_global_load_lds(
        (const __attribute__((address_space(1))) void*)g,
        (__attribute__((address_space(3))) void*)l, 16, 0, 0);
}

// ---------------------------------------------------------------------------
// fp32 -> bf16 convert, 7 segments in one launch
// ---------------------------------------------------------------------------
struct CvtSeg { const float* s; unsigned short* d; int n; };
struct Cvt7 { CvtSeg seg[7]; };

__global__ __launch_bounds__(256) void cvt_kernel(Cvt7 a) {
    const CvtSeg c = a.seg[blockIdx.y];
    const int stride = gridDim.x * 256 * 4;
    for (int i = (blockIdx.x * 256 + threadIdx.x) * 4; i < c.n; i += stride) {
        float4v v = *(const float4v*)(c.s + i);
        ushort4v u;
        u.x = f2bf(v.x); u.y = f2bf(v.y); u.z = f2bf(v.z); u.w = f2bf(v.w);
        *(ushort4v*)(c.d + i) = u;
    }
}

// ---------------------------------------------------------------------------
// 128x128-tile GEMM (QKV projections): C = (A W^T + bias) * scale, bf16 out.
// ---------------------------------------------------------------------------
__device__ __forceinline__ void gemm128_body(const unsigned short* __restrict__ A,
                                             const unsigned short* __restrict__ W,
                                             const float* __restrict__ bias,
                                             unsigned short* __restrict__ Cout,
                                             int N, int K, float scale,
                                             unsigned short* As, unsigned short* Ws) {
    const int t = threadIdx.x;
    const int w = t >> 6, lane = t & 63;
    const int quad = lane >> 4, l16 = lane & 15;
    const int m0 = blockIdx.x * 128, n0 = blockIdx.y * 128;
    const int wm = (w >> 1) * 64, wn = (w & 1) * 64;

    float4v acc[4][4];
    for (int i = 0; i < 4; ++i)
        for (int j = 0; j < 4; ++j) acc[i][j] = float4v{0.f, 0.f, 0.f, 0.f};

    const int srow = lane >> 3;
    const int scol = (lane & 7) * 8;

    for (int k0 = 0; k0 < K; k0 += 64) {
        __syncthreads();
        for (int i = 0; i < 4; ++i) {
            const int c = w * 4 + i;
            gl_lds16(A + (size_t)(m0 + c * 8 + srow) * K + k0 + scol,
                     &As[c * 512 + lane * 8]);
            gl_lds16(W + (size_t)(n0 + c * 8 + srow) * K + k0 + scol,
                     &Ws[c * 512 + lane * 8]);
        }
        __syncthreads();
        for (int ks = 0; ks < 2; ++ks) {
            bf16x8 af[4], wf[4];
            for (int i = 0; i < 4; ++i)
                af[i] = *(const bf16x8*)&As[(wm + i * 16 + l16) * 64 + ks * 32 + quad * 8];
            for (int i = 0; i < 4; ++i)
                wf[i] = *(const bf16x8*)&Ws[(wn + i * 16 + l16) * 64 + ks * 32 + quad * 8];
            for (int mi = 0; mi < 4; ++mi)
                for (int ni = 0; ni < 4; ++ni)
                    acc[mi][ni] = MFMA16(af[mi], wf[ni], acc[mi][ni]);
        }
    }

    for (int mi = 0; mi < 4; ++mi)
        for (int ni = 0; ni < 4; ++ni) {
            const int col = n0 + wn + ni * 16 + l16;
            const float bv = bias[col];
            for (int reg = 0; reg < 4; ++reg) {
                const int row = m0 + wm + mi * 16 + quad * 4 + reg;
                Cout[(size_t)row * N + col] = f2bf((acc[mi][ni][reg] + bv) * scale);
            }
        }
}

__global__ __launch_bounds__(256) void gemm_qkv_kernel(
    const unsigned short* qa, const unsigned short* ka, const unsigned short* va,
    const unsigned short* Wqb, const unsigned short* Wkb, const unsigned short* Wvb,
    const float* bq, const float* bk, const float* bv,
    unsigned short* Qb, unsigned short* Kb, unsigned short* Vb, float qscale) {
    __shared__ unsigned short As[128 * 64];
    __shared__ unsigned short Ws[128 * 64];
    const int z = blockIdx.z;
    const unsigned short* A = z == 0 ? qa : (z == 1 ? ka : va);
    const unsigned short* W = z == 0 ? Wqb : (z == 1 ? Wkb : Wvb);
    const float* bias = z == 0 ? bq : (z == 1 ? bk : bv);
    unsigned short* C = z == 0 ? Qb : (z == 1 ? Kb : Vb);
    gemm128_body(A, W, bias, C, 1024, 1024, z == 0 ? qscale : 1.0f, As, Ws);
}

// ---------------------------------------------------------------------------
// 64x128-tile GEMM (output projection, fp32 out). 512 blocks = 2 blocks/CU.
// ---------------------------------------------------------------------------
__global__ __launch_bounds__(256) void gemm_out_kernel(const unsigned short* __restrict__ A,
                                                       const unsigned short* __restrict__ W,
                                                       const float* __restrict__ bias,
                                                       float* __restrict__ Cout) {
    __shared__ unsigned short As[64 * 64];
    __shared__ unsigned short Ws[128 * 64];
    const int N = 1024, K = 1024;
    const int t = threadIdx.x;
    const int w = t >> 6, lane = t & 63;
    const int quad = lane >> 4, l16 = lane & 15;
    const int m0 = blockIdx.x * 64, n0 = blockIdx.y * 128;
    const int wm = (w & 1) * 32, wn = (w >> 1) * 64;

    float4v acc[2][4];
    for (int i = 0; i < 2; ++i)
        for (int j = 0; j < 4; ++j) acc[i][j] = float4v{0.f, 0.f, 0.f, 0.f};

    const int srow = lane >> 3;
    const int scol = (lane & 7) * 8;

    for (int k0 = 0; k0 < K; k0 += 64) {
        __syncthreads();
        for (int i = 0; i < 2; ++i) {
            const int c = w * 2 + i;
            gl_lds16(A + (size_t)(m0 + c * 8 + srow) * K + k0 + scol,
                     &As[c * 512 + lane * 8]);
        }
        for (int i = 0; i < 4; ++i) {
            const int c = w * 4 + i;
            gl_lds16(W + (size_t)(n0 + c * 8 + srow) * K + k0 + scol,
                     &Ws[c * 512 + lane * 8]);
        }
        __syncthreads();
        for (int ks = 0; ks < 2; ++ks) {
            bf16x8 af[2], wf[4];
            for (int i = 0; i < 2; ++i)
                af[i] = *(const bf16x8*)&As[(wm + i * 16 + l16) * 64 + ks * 32 + quad * 8];
            for (int i = 0; i < 4; ++i)
                wf[i] = *(const bf16x8*)&Ws[(wn + i * 16 + l16) * 64 + ks * 32 + quad * 8];
            for (int mi = 0; mi < 2; ++mi)
                for (int ni = 0; ni < 4; ++ni)
                    acc[mi][ni] = MFMA16(af[mi], wf[ni], acc[mi][ni]);
        }
    }

    for (int mi = 0; mi < 2; ++mi)
        for (int ni = 0; ni < 4; ++ni) {
            const int col = n0 + wn + ni * 16 + l16;
            const float bv = bias[col];
            for (int reg = 0; reg < 4; ++reg) {
                const int row = m0 + wm + mi * 16 + quad * 4 + reg;
                Cout[(size_t)row * N + col] = acc[mi][ni][reg] + bv;
            }
        }
}

// ---------------------------------------------------------------------------
// Flash attention, no-max softmax, split-K-2, 64-row q tiles.
// Grid 2048; LDS 27.6 KB -> 5 blocks/CU (20 waves/CU). Row-sum l accumulated
// in registers (per-lane partial over l16-subset; shfl-reduced at the end) --
// no ones-column, Vt is 64 rows. Partials Op (fp32) + Lp; combine adds.
// ---------------------------------------------------------------------------
__global__ __launch_bounds__(256) void attn_kernel(const unsigned short* __restrict__ Q,
                                                   const unsigned short* __restrict__ Kg,
                                                   const unsigned short* __restrict__ Vg,
                                                   const unsigned char* __restrict__ mask,
                                                   float* __restrict__ Op,
                                                   float* __restrict__ Lp) {
    const int bid = blockIdx.x;
    const int bh = bid & 31;         // fastest -> XCD L2 locality for K/V
    const int sp = (bid >> 5) & 1;   // key-range split
    const int qt = bid >> 6;         // 0..31 (64-row q tile)
    const int b = bh >> 4, h = bh & 15;
    const int t = threadIdx.x, w = t >> 6, lane = t & 63;
    const int quad = lane >> 4, l16 = lane & 15;

    __shared__ unsigned short Ps[64][72];  // Q at start, then P (wave-private rows)
    __shared__ unsigned short Ks[64][72];
    __shared__ unsigned short Vt[64][72];  // transposed V: Vt[d][k]

    const int kbase = sp * 1024;
    const unsigned short* Qp = Q + ((size_t)(b * 2048 + qt * 64)) * 1024 + h * 64;
    const unsigned short* Kp = Kg + ((size_t)(b * 2048 + kbase)) * 1024 + h * 64;
    const unsigned short* Vp = Vg + ((size_t)(b * 2048 + kbase)) * 1024 + h * 64;
    const unsigned char* Mp = mask + (size_t)(b * 2048 + qt * 64) * 2048 + kbase;

    {   // Q tile 64x64
        const int r = t >> 3, c8 = (t & 7) * 8;
        *(uint4*)&Ps[r][c8] = *(const uint4*)(Qp + (size_t)r * 1024 + c8);
        *(uint4*)&Ps[r + 32][c8] = *(const uint4*)(Qp + (size_t)(r + 32) * 1024 + c8);
    }
    __syncthreads();
    bf16x8 qf[2];
    qf[0] = *(const bf16x8*)&Ps[w * 16 + l16][quad * 8];
    qf[1] = *(const bf16x8*)&Ps[w * 16 + l16][32 + quad * 8];

    float4v o[4];
    for (int i = 0; i < 4; ++i) o[i] = float4v{0.f, 0.f, 0.f, 0.f};
    float4v l_acc = float4v{0.f, 0.f, 0.f, 0.f};  // per-lane l partial (l16 subset)

    const int sr = t >> 3, sc8 = (t & 7) * 8;          // K staging map
    const int vkk = (t & 31) * 2, vd0 = (t >> 5) * 8;  // V staging map
    const int mrow = w * 16 + (lane >> 2);             // mask probe: 16 rows x 64 B
    const int mc0 = (lane & 3) * 16;

    uint4 kreg0, kreg1, vreg0, vreg1, mreg;
    {
        kreg0 = *(const uint4*)(Kp + (size_t)sr * 1024 + sc8);
        kreg1 = *(const uint4*)(Kp + (size_t)(sr + 32) * 1024 + sc8);
        vreg0 = *(const uint4*)(Vp + (size_t)vkk * 1024 + vd0);
        vreg1 = *(const uint4*)(Vp + (size_t)(vkk + 1) * 1024 + vd0);
        mreg  = *(const uint4*)(Mp + (size_t)mrow * 2048 + mc0);
    }

    for (int kc = 0; kc < 1024; kc += 64) {
        __syncthreads();  // prev iter's LDS readers done
        *(uint4*)&Ks[sr][sc8] = kreg0;
        *(uint4*)&Ks[sr + 32][sc8] = kreg1;
        {
            const unsigned short* pa = (const unsigned short*)&vreg0;
            const unsigned short* pb = (const unsigned short*)&vreg1;
            for (int j = 0; j < 8; ++j)
                *(unsigned int*)&Vt[vd0 + j][vkk] =
                    (unsigned int)pa[j] | ((unsigned int)pb[j] << 16);
        }
        const bool anymask = __any((mreg.x | mreg.y | mreg.z | mreg.w) != 0);
        __syncthreads();  // staged data visible

        const int kn = kc + 64;
        if (kn < 1024) {  // prefetch next tile
            kreg0 = *(const uint4*)(Kp + (size_t)(kn + sr) * 1024 + sc8);
            kreg1 = *(const uint4*)(Kp + (size_t)(kn + sr + 32) * 1024 + sc8);
            vreg0 = *(const uint4*)(Vp + (size_t)(kn + vkk) * 1024 + vd0);
            vreg1 = *(const uint4*)(Vp + (size_t)(kn + vkk + 1) * 1024 + vd0);
            mreg  = *(const uint4*)(Mp + (size_t)mrow * 2048 + kn + mc0);
        }

        // S = Q K^T : wave's 16 rows x 64 keys (log2 domain)
        float4v s[4];
        for (int nt = 0; nt < 4; ++nt) {
            const float4v z4 = float4v{0.f, 0.f, 0.f, 0.f};
            bf16x8 kf = *(const bf16x8*)&Ks[nt * 16 + l16][quad * 8];
            s[nt] = MFMA16(qf[0], kf, z4);
            kf = *(const bf16x8*)&Ks[nt * 16 + l16][32 + quad * 8];
            s[nt] = MFMA16(qf[1], kf, s[nt]);
        }

        // no-max softmax: P = exp2(s); l accumulates in-register
        for (int reg = 0; reg < 4; ++reg) {
            float sv[4];
            for (int nt = 0; nt < 4; ++nt) sv[nt] = s[nt][reg];
            if (anymask) {  // rare slow path
                const unsigned char* mr =
                    Mp + (size_t)(w * 16 + quad * 4 + reg) * 2048 + kc;
                for (int nt = 0; nt < 4; ++nt)
                    if (mr[nt * 16 + l16]) sv[nt] = -1e18f;
            }
            float rs = 0.f;
            for (int nt = 0; nt < 4; ++nt) {
                const float pe = fast_exp2(sv[nt]);
                rs += pe;
                Ps[w * 16 + quad * 4 + reg][nt * 16 + l16] = f2bf(pe);
            }
            l_acc[reg] += rs;
        }

        // O += P V  (Ps rows are wave-private; DS ops in-order per wave)
        for (int ks = 0; ks < 2; ++ks) {
            bf16x8 pf = *(const bf16x8*)&Ps[w * 16 + l16][ks * 32 + quad * 8];
            for (int dt = 0; dt < 4; ++dt) {
                bf16x8 vf = *(const bf16x8*)&Vt[dt * 16 + l16][ks * 32 + quad * 8];
                o[dt] = MFMA16(pf, vf, o[dt]);
            }
        }
    }

    // l: reduce per-lane partials across the 16 lanes of each quad-row group
    float lr[4];
    for (int reg = 0; reg < 4; ++reg) {
        float l = l_acc[reg];
        l += __shfl_xor(l, 1);
        l += __shfl_xor(l, 2);
        l += __shfl_xor(l, 4);
        l += __shfl_xor(l, 8);
        lr[reg] = l;
    }

    // epilogue: unnormalized O (fp32) + row-sum partials
    float* Opp = Op + (size_t)sp * 4096 * 1024;
    float* Lpp = Lp + (size_t)sp * 65536;
    for (int reg = 0; reg < 4; ++reg) {
        const int grow = b * 2048 + qt * 64 + w * 16 + quad * 4 + reg;
        if (l16 == 0) Lpp[(size_t)grow * 16 + h] = lr[reg];
    }
    for (int dt = 0; dt < 4; ++dt) {
        const int dcol = dt * 16 + l16;
        for (int reg = 0; reg < 4; ++reg) {
            const int grow = b * 2048 + qt * 64 + w * 16 + quad * 4 + reg;
            Opp[(size_t)grow * 1024 + h * 64 + dcol] = o[dt][reg];
        }
    }
}

// ---------------------------------------------------------------------------
// Combine split-K partials: Cb = bf16((O0+O1) / (l0+l1))
// ---------------------------------------------------------------------------
__global__ __launch_bounds__(256) void combine_kernel(const float* __restrict__ Op,
                                                      const float* __restrict__ Lp,
                                                      unsigned short* __restrict__ Cb) {
    const size_t e = ((size_t)blockIdx.x * 256 + threadIdx.x) * 4;
    const int row = (int)(e >> 10);
    const int h = ((int)e & 1023) >> 6;
    float4v a = *(const float4v*)(Op + e);
    float4v bq = *(const float4v*)(Op + (size_t)4096 * 1024 + e);
    const float inv = 1.0f / (Lp[(size_t)row * 16 + h] + Lp[65536 + (size_t)row * 16 + h]);
    ushort4v u;
    u.x = f2bf((a.x + bq.x) * inv);
    u.y = f2bf((a.y + bq.y) * inv);
    u.z = f2bf((a.z + bq.z) * inv);
    u.w = f2bf((a.w + bq.w) * inv);
    *(ushort4v*)(Cb + e) = u;
}

extern "C" void kernel_launch(void* const* d_in, const int* in_sizes, int n_in,
                              void* d_out, int out_size, void* d_ws, size_t ws_size,
                              hipStream_t stream) {
    (void)in_sizes; (void)n_in; (void)out_size; (void)ws_size;
    const float* query = (const float*)d_in[0];
    const float* key   = (const float*)d_in[1];
    const float* value = (const float*)d_in[2];
    const unsigned char* mask = (const unsigned char*)d_in[3];
    const float* Wq = (const float*)d_in[4];
    const float* bq = (const float*)d_in[5];
    const float* Wk = (const float*)d_in[6];
    const float* bk = (const float*)d_in[7];
    const float* Wv = (const float*)d_in[8];
    const float* bv = (const float*)d_in[9];
    const float* Wo = (const float*)d_in[10];
    const float* bo = (const float*)d_in[11];

    const size_t MD = (size_t)4096 * 1024;
    const size_t WD = (size_t)1024 * 1024;

    unsigned short* Qb  = (unsigned short*)d_ws;   // projected Q/K/V (bf16)
    unsigned short* Kb  = Qb + MD;
    unsigned short* Vb  = Kb + MD;
    unsigned short* qb  = Vb + MD;                 // bf16 inputs (dead after qkv)
    unsigned short* kb  = qb + MD;
    unsigned short* vb  = kb + MD;
    unsigned short* Wqb = vb + MD;                 // dead after qkv
    unsigned short* Wkb = Wqb + WD;
    unsigned short* Wvb = Wkb + WD;
    float* Op = (float*)qb;                        // 2*MD floats, aliases qb..Wvb+pad
    unsigned short* Wob = qb + 4 * MD;             // after Op region
    unsigned short* Cb  = Wob + WD;
    float* Lp = (float*)(Cb + MD);                 // 2*65536 floats

    Cvt7 cv;
    cv.seg[0] = {query, qb, (int)MD};
    cv.seg[1] = {key,   kb, (int)MD};
    cv.seg[2] = {value, vb, (int)MD};
    cv.seg[3] = {Wq, Wqb, (int)WD};
    cv.seg[4] = {Wk, Wkb, (int)WD};
    cv.seg[5] = {Wv, Wvb, (int)WD};
    cv.seg[6] = {Wo, Wob, (int)WD};
    cvt_kernel<<<dim3(1024, 7), 256, 0, stream>>>(cv);

    // Q scale = (1/sqrt(64)) * log2(e); scores then live in log2 domain
    const float qscale = 0.125f * 1.44269504088896f;
    gemm_qkv_kernel<<<dim3(32, 8, 3), 256, 0, stream>>>(
        qb, kb, vb, Wqb, Wkb, Wvb, bq, bk, bv, Qb, Kb, Vb, qscale);

    attn_kernel<<<dim3(2048), 256, 0, stream>>>(Qb, Kb, Vb, mask, Op, Lp);

    combine_kernel<<<dim3(4096), 256, 0, stream>>>(Op, Lp, Cb);

    gemm_out_kernel<<<dim3(64, 8), 256, 0, stream>>>(Cb, Wob, bo, (float*)d_out);
}

// Round 7
// 268.587 us; speedup vs baseline: 1.0533x; 1.0533x over previous
//
#include <hip/hip_runtime.h>
#include <hip/hip_bf16.h>

typedef __attribute__((ext_vector_type(4))) float float4v;
typedef __attribute__((ext_vector_type(8))) __bf16 bf16x8;
typedef __attribute__((ext_vector_type(4))) unsigned short ushort4v;

#define MFMA16(a, b, c) __builtin_amdgcn_mfma_f32_16x16x32_bf16(a, b, c, 0, 0, 0)

__device__ __forceinline__ unsigned short f2bf(float f) {
    return __builtin_bit_cast(unsigned short, (__bf16)f);
}

// 2^x via native v_exp_f32 (args bounded above by ~13; may be -1e18 -> 0)
__device__ __forceinline__ float fast_exp2(float x) {
#if __has_builtin(__builtin_amdgcn_exp2f)
    return __builtin_amdgcn_exp2f(x);
#else
    return exp2f(x);
#endif
}

// async global->LDS, 16B per lane; lds dest must be wave-uniform base + lane*16
__device__ __forceinline__ void gl_lds16(const unsigned short* g, unsigned short* l) {
    __builtin_amdgcn_global_load_lds(
        (const __attribute__((address_space(1))) void*)g,
        (__attribute__((address_space(3))) void*)l, 16, 0, 0);
}

// ---------------------------------------------------------------------------
// fp32 -> bf16 convert, 7 segments in one launch
// ---------------------------------------------------------------------------
struct CvtSeg { const float* s; unsigned short* d; int n; };
struct Cvt7 { CvtSeg seg[7]; };

__global__ __launch_bounds__(256) void cvt_kernel(Cvt7 a) {
    const CvtSeg c = a.seg[blockIdx.y];
    const int stride = gridDim.x * 256 * 4;
    for (int i = (blockIdx.x * 256 + threadIdx.x) * 4; i < c.n; i += stride) {
        float4v v = *(const float4v*)(c.s + i);
        ushort4v u;
        u.x = f2bf(v.x); u.y = f2bf(v.y); u.z = f2bf(v.z); u.w = f2bf(v.w);
        *(ushort4v*)(c.d + i) = u;
    }
}

// ---------------------------------------------------------------------------
// 128x128-tile GEMM (QKV projections): C = (A W^T + bias) * scale, bf16 out.
// ---------------------------------------------------------------------------
__device__ __forceinline__ void gemm128_body(const unsigned short* __restrict__ A,
                                             const unsigned short* __restrict__ W,
                                             const float* __restrict__ bias,
                                             unsigned short* __restrict__ Cout,
                                             int N, int K, float scale,
                                             unsigned short* As, unsigned short* Ws) {
    const int t = threadIdx.x;
    const int w = t >> 6, lane = t & 63;
    const int quad = lane >> 4, l16 = lane & 15;
    const int m0 = blockIdx.x * 128, n0 = blockIdx.y * 128;
    const int wm = (w >> 1) * 64, wn = (w & 1) * 64;

    float4v acc[4][4];
    for (int i = 0; i < 4; ++i)
        for (int j = 0; j < 4; ++j) acc[i][j] = float4v{0.f, 0.f, 0.f, 0.f};

    const int srow = lane >> 3;
    const int scol = (lane & 7) * 8;

    for (int k0 = 0; k0 < K; k0 += 64) {
        __syncthreads();
        for (int i = 0; i < 4; ++i) {
            const int c = w * 4 + i;
            gl_lds16(A + (size_t)(m0 + c * 8 + srow) * K + k0 + scol,
                     &As[c * 512 + lane * 8]);
            gl_lds16(W + (size_t)(n0 + c * 8 + srow) * K + k0 + scol,
                     &Ws[c * 512 + lane * 8]);
        }
        __syncthreads();
        for (int ks = 0; ks < 2; ++ks) {
            bf16x8 af[4], wf[4];
            for (int i = 0; i < 4; ++i)
                af[i] = *(const bf16x8*)&As[(wm + i * 16 + l16) * 64 + ks * 32 + quad * 8];
            for (int i = 0; i < 4; ++i)
                wf[i] = *(const bf16x8*)&Ws[(wn + i * 16 + l16) * 64 + ks * 32 + quad * 8];
            for (int mi = 0; mi < 4; ++mi)
                for (int ni = 0; ni < 4; ++ni)
                    acc[mi][ni] = MFMA16(af[mi], wf[ni], acc[mi][ni]);
        }
    }

    for (int mi = 0; mi < 4; ++mi)
        for (int ni = 0; ni < 4; ++ni) {
            const int col = n0 + wn + ni * 16 + l16;
            const float bv = bias[col];
            for (int reg = 0; reg < 4; ++reg) {
                const int row = m0 + wm + mi * 16 + quad * 4 + reg;
                Cout[(size_t)row * N + col] = f2bf((acc[mi][ni][reg] + bv) * scale);
            }
        }
}

__global__ __launch_bounds__(256) void gemm_qkv_kernel(
    const unsigned short* qa, const unsigned short* ka, const unsigned short* va,
    const unsigned short* Wqb, const unsigned short* Wkb, const unsigned short* Wvb,
    const float* bq, const float* bk, const float* bv,
    unsigned short* Qb, unsigned short* Kb, unsigned short* Vb, float qscale) {
    __shared__ unsigned short As[128 * 64];
    __shared__ unsigned short Ws[128 * 64];
    const int z = blockIdx.z;
    const unsigned short* A = z == 0 ? qa : (z == 1 ? ka : va);
    const unsigned short* W = z == 0 ? Wqb : (z == 1 ? Wkb : Wvb);
    const float* bias = z == 0 ? bq : (z == 1 ? bk : bv);
    unsigned short* C = z == 0 ? Qb : (z == 1 ? Kb : Vb);
    gemm128_body(A, W, bias, C, 1024, 1024, z == 0 ? qscale : 1.0f, As, Ws);
}

// ---------------------------------------------------------------------------
// 64x128-tile GEMM (output projection, fp32 out). 512 blocks = 2 blocks/CU.
// ---------------------------------------------------------------------------
__global__ __launch_bounds__(256) void gemm_out_kernel(const unsigned short* __restrict__ A,
                                                       const unsigned short* __restrict__ W,
                                                       const float* __restrict__ bias,
                                                       float* __restrict__ Cout) {
    __shared__ unsigned short As[64 * 64];
    __shared__ unsigned short Ws[128 * 64];
    const int N = 1024, K = 1024;
    const int t = threadIdx.x;
    const int w = t >> 6, lane = t & 63;
    const int quad = lane >> 4, l16 = lane & 15;
    const int m0 = blockIdx.x * 64, n0 = blockIdx.y * 128;
    const int wm = (w & 1) * 32, wn = (w >> 1) * 64;

    float4v acc[2][4];
    for (int i = 0; i < 2; ++i)
        for (int j = 0; j < 4; ++j) acc[i][j] = float4v{0.f, 0.f, 0.f, 0.f};

    const int srow = lane >> 3;
    const int scol = (lane & 7) * 8;

    for (int k0 = 0; k0 < K; k0 += 64) {
        __syncthreads();
        for (int i = 0; i < 2; ++i) {
            const int c = w * 2 + i;
            gl_lds16(A + (size_t)(m0 + c * 8 + srow) * K + k0 + scol,
                     &As[c * 512 + lane * 8]);
        }
        for (int i = 0; i < 4; ++i) {
            const int c = w * 4 + i;
            gl_lds16(W + (size_t)(n0 + c * 8 + srow) * K + k0 + scol,
                     &Ws[c * 512 + lane * 8]);
        }
        __syncthreads();
        for (int ks = 0; ks < 2; ++ks) {
            bf16x8 af[2], wf[4];
            for (int i = 0; i < 2; ++i)
                af[i] = *(const bf16x8*)&As[(wm + i * 16 + l16) * 64 + ks * 32 + quad * 8];
            for (int i = 0; i < 4; ++i)
                wf[i] = *(const bf16x8*)&Ws[(wn + i * 16 + l16) * 64 + ks * 32 + quad * 8];
            for (int mi = 0; mi < 2; ++mi)
                for (int ni = 0; ni < 4; ++ni)
                    acc[mi][ni] = MFMA16(af[mi], wf[ni], acc[mi][ni]);
        }
    }

    for (int mi = 0; mi < 2; ++mi)
        for (int ni = 0; ni < 4; ++ni) {
            const int col = n0 + wn + ni * 16 + l16;
            const float bv = bias[col];
            for (int reg = 0; reg < 4; ++reg) {
                const int row = m0 + wm + mi * 16 + quad * 4 + reg;
                Cout[(size_t)row * N + col] = acc[mi][ni][reg] + bv;
            }
        }
}

// ---------------------------------------------------------------------------
// Flash attention, S^T formulation. QK^T computed as K*Q^T (swapped MFMA
// operands) so each lane holds 4 CONSECUTIVE keys per q-column: exp2'd P is
// packed in-register and written as one ds_write_b64 directly into A-operand
// layout Pt[q][key] -> PV reads ds_read_b128. l = scalar per-lane accumulator
// (q = l16), shfl-reduced once at the end. No split-K, no combine kernel.
// Grid: 1024 blocks (bh fastest for XCD L2 locality), 64 q-rows per block.
// ---------------------------------------------------------------------------
__global__ __launch_bounds__(256) void attn_kernel(const unsigned short* __restrict__ Q,
                                                   const unsigned short* __restrict__ Kg,
                                                   const unsigned short* __restrict__ Vg,
                                                   const unsigned char* __restrict__ mask,
                                                   unsigned short* __restrict__ Ctx) {
    const int bid = blockIdx.x;
    const int bh = bid & 31;   // fastest -> same-XCD blocks share (b,h) K/V
    const int qt = bid >> 5;   // 0..31 (64-row q tile)
    const int b = bh >> 4, h = bh & 15;
    const int t = threadIdx.x, w = t >> 6, lane = t & 63;
    const int quad = lane >> 4, l16 = lane & 15;

    __shared__ unsigned short Pt[64][72];  // Q at start; then P in A-layout [q][key]
    __shared__ unsigned short Ks[64][72];
    __shared__ unsigned short Vt[64][72];  // transposed V: Vt[d][k]

    const unsigned short* Qp = Q + ((size_t)(b * 2048 + qt * 64)) * 1024 + h * 64;
    const unsigned short* Kp = Kg + ((size_t)b * 2048) * 1024 + h * 64;
    const unsigned short* Vp = Vg + ((size_t)b * 2048) * 1024 + h * 64;
    const unsigned char* Mp = mask + (size_t)(b * 2048 + qt * 64) * 2048;

    {   // Q tile 64x64 -> Pt
        const int r = t >> 3, c8 = (t & 7) * 8;
        *(uint4*)&Pt[r][c8] = *(const uint4*)(Qp + (size_t)r * 1024 + c8);
        *(uint4*)&Pt[r + 32][c8] = *(const uint4*)(Qp + (size_t)(r + 32) * 1024 + c8);
    }
    __syncthreads();
    // qf = B-operand fragment (n = q = l16); rows of Pt are wave-private after this
    bf16x8 qf[2];
    qf[0] = *(const bf16x8*)&Pt[w * 16 + l16][quad * 8];
    qf[1] = *(const bf16x8*)&Pt[w * 16 + l16][32 + quad * 8];

    float4v o[4];
    for (int i = 0; i < 4; ++i) o[i] = float4v{0.f, 0.f, 0.f, 0.f};
    float l_acc = 0.f;  // per-lane partial row-sum for q = l16

    const int sr = t >> 3, sc8 = (t & 7) * 8;          // K staging map
    const int vkk = (t & 31) * 2, vd0 = (t >> 5) * 8;  // V staging map
    const int mrow = w * 16 + (lane >> 2);             // mask probe: 16 rows x 64 B
    const int mc0 = (lane & 3) * 16;

    uint4 kreg0, kreg1, vreg0, vreg1, mreg;
    {
        kreg0 = *(const uint4*)(Kp + (size_t)sr * 1024 + sc8);
        kreg1 = *(const uint4*)(Kp + (size_t)(sr + 32) * 1024 + sc8);
        vreg0 = *(const uint4*)(Vp + (size_t)vkk * 1024 + vd0);
        vreg1 = *(const uint4*)(Vp + (size_t)(vkk + 1) * 1024 + vd0);
        mreg  = *(const uint4*)(Mp + (size_t)mrow * 2048 + mc0);
    }

    for (int kc = 0; kc < 2048; kc += 64) {
        __syncthreads();  // prev iter's Ks/Vt readers done
        *(uint4*)&Ks[sr][sc8] = kreg0;
        *(uint4*)&Ks[sr + 32][sc8] = kreg1;
        {
            const unsigned short* pa = (const unsigned short*)&vreg0;
            const unsigned short* pb = (const unsigned short*)&vreg1;
            for (int j = 0; j < 8; ++j)
                *(unsigned int*)&Vt[vd0 + j][vkk] =
                    (unsigned int)pa[j] | ((unsigned int)pb[j] << 16);
        }
        const bool anymask = __any((mreg.x | mreg.y | mreg.z | mreg.w) != 0);
        __syncthreads();  // staged data visible

        const int kn = kc + 64;
        if (kn < 2048) {  // prefetch next tile
            kreg0 = *(const uint4*)(Kp + (size_t)(kn + sr) * 1024 + sc8);
            kreg1 = *(const uint4*)(Kp + (size_t)(kn + sr + 32) * 1024 + sc8);
            vreg0 = *(const uint4*)(Vp + (size_t)(kn + vkk) * 1024 + vd0);
            vreg1 = *(const uint4*)(Vp + (size_t)(kn + vkk + 1) * 1024 + vd0);
            mreg  = *(const uint4*)(Mp + (size_t)mrow * 2048 + kn + mc0);
        }

        // S^T = K Q^T : lane holds S^T[key = nt*16+quad*4+reg][q = l16]
        float4v s[4];
        for (int nt = 0; nt < 4; ++nt) {
            const float4v z4 = float4v{0.f, 0.f, 0.f, 0.f};
            bf16x8 kf = *(const bf16x8*)&Ks[nt * 16 + l16][quad * 8];
            s[nt] = MFMA16(kf, qf[0], z4);
            kf = *(const bf16x8*)&Ks[nt * 16 + l16][32 + quad * 8];
            s[nt] = MFMA16(kf, qf[1], s[nt]);
        }

        // exp2 + pack 4 consecutive keys -> one b64 store in A-layout
        for (int nt = 0; nt < 4; ++nt) {
            float p0 = s[nt][0], p1 = s[nt][1], p2 = s[nt][2], p3 = s[nt][3];
            if (anymask) {  // rare slow path: scalar byte re-read
                const unsigned char* mr =
                    Mp + (size_t)(w * 16 + l16) * 2048 + kc + nt * 16 + quad * 4;
                if (mr[0]) p0 = -1e18f;
                if (mr[1]) p1 = -1e18f;
                if (mr[2]) p2 = -1e18f;
                if (mr[3]) p3 = -1e18f;
            }
            const float e0 = fast_exp2(p0), e1 = fast_exp2(p1);
            const float e2 = fast_exp2(p2), e3 = fast_exp2(p3);
            l_acc += (e0 + e1) + (e2 + e3);
            uint2 u;
            u.x = (unsigned int)f2bf(e0) | ((unsigned int)f2bf(e1) << 16);
            u.y = (unsigned int)f2bf(e2) | ((unsigned int)f2bf(e3) << 16);
            *(uint2*)&Pt[w * 16 + l16][nt * 16 + quad * 4] = u;  // wave-private row
        }

        // O += P V ; pf is the A-layout fragment we just wrote (same-wave DS order)
        for (int ks = 0; ks < 2; ++ks) {
            bf16x8 pf = *(const bf16x8*)&Pt[w * 16 + l16][ks * 32 + quad * 8];
            for (int dt = 0; dt < 4; ++dt) {
                bf16x8 vf = *(const bf16x8*)&Vt[dt * 16 + l16][ks * 32 + quad * 8];
                o[dt] = MFMA16(pf, vf, o[dt]);
            }
        }
    }

    // l: sum the 4 quad-partials for each q = l16 (columns are spread over quads)
    float lfull = l_acc;
    lfull += __shfl_xor(lfull, 16);
    lfull += __shfl_xor(lfull, 32);
    // O rows are q = quad*4+reg: fetch l from the lane holding that q as l16
    float inv[4];
    for (int reg = 0; reg < 4; ++reg)
        inv[reg] = 1.0f / __shfl(lfull, (lane & 48) | (quad * 4 + reg));

    for (int dt = 0; dt < 4; ++dt) {
        const int dcol = dt * 16 + l16;
        for (int reg = 0; reg < 4; ++reg) {
            const int ql = w * 16 + quad * 4 + reg;
            Ctx[((size_t)(b * 2048 + qt * 64 + ql)) * 1024 + h * 64 + dcol] =
                f2bf(o[dt][reg] * inv[reg]);
        }
    }
}

extern "C" void kernel_launch(void* const* d_in, const int* in_sizes, int n_in,
                              void* d_out, int out_size, void* d_ws, size_t ws_size,
                              hipStream_t stream) {
    (void)in_sizes; (void)n_in; (void)out_size; (void)ws_size;
    const float* query = (const float*)d_in[0];
    const float* key   = (const float*)d_in[1];
    const float* value = (const float*)d_in[2];
    const unsigned char* mask = (const unsigned char*)d_in[3];
    const float* Wq = (const float*)d_in[4];
    const float* bq = (const float*)d_in[5];
    const float* Wk = (const float*)d_in[6];
    const float* bk = (const float*)d_in[7];
    const float* Wv = (const float*)d_in[8];
    const float* bv = (const float*)d_in[9];
    const float* Wo = (const float*)d_in[10];
    const float* bo = (const float*)d_in[11];

    const size_t MD = (size_t)4096 * 1024;
    const size_t WD = (size_t)1024 * 1024;

    unsigned short* Qb  = (unsigned short*)d_ws;   // projected Q/K/V (bf16)
    unsigned short* Kb  = Qb + MD;
    unsigned short* Vb  = Kb + MD;
    unsigned short* qb  = Vb + MD;                 // bf16 inputs (dead after qkv)
    unsigned short* kb  = qb + MD;
    unsigned short* vb  = kb + MD;
    unsigned short* Wqb = vb + MD;
    unsigned short* Wkb = Wqb + WD;
    unsigned short* Wvb = Wkb + WD;
    unsigned short* Wob = Wvb + WD;
    unsigned short* Cb  = qb;                      // context aliases qb (dead by then)

    Cvt7 cv;
    cv.seg[0] = {query, qb, (int)MD};
    cv.seg[1] = {key,   kb, (int)MD};
    cv.seg[2] = {value, vb, (int)MD};
    cv.seg[3] = {Wq, Wqb, (int)WD};
    cv.seg[4] = {Wk, Wkb, (int)WD};
    cv.seg[5] = {Wv, Wvb, (int)WD};
    cv.seg[6] = {Wo, Wob, (int)WD};
    cvt_kernel<<<dim3(1024, 7), 256, 0, stream>>>(cv);

    // Q scale = (1/sqrt(64)) * log2(e); scores then live in log2 domain
    const float qscale = 0.125f * 1.44269504088896f;
    gemm_qkv_kernel<<<dim3(32, 8, 3), 256, 0, stream>>>(
        qb, kb, vb, Wqb, Wkb, Wvb, bq, bk, bv, Qb, Kb, Vb, qscale);

    attn_kernel<<<dim3(1024), 256, 0, stream>>>(Qb, Kb, Vb, mask, Cb);

    gemm_out_kernel<<<dim3(64, 8), 256, 0, stream>>>(Cb, Wob, bo, (float*)d_out);
}

// Round 8
// 267.819 us; speedup vs baseline: 1.0563x; 1.0029x over previous
//
#include <hip/hip_runtime.h>
#include <hip/hip_bf16.h>

typedef __attribute__((ext_vector_type(4))) float float4v;
typedef __attribute__((ext_vector_type(8))) __bf16 bf16x8;
typedef __attribute__((ext_vector_type(4))) unsigned short ushort4v;

#define MFMA16(a, b, c) __builtin_amdgcn_mfma_f32_16x16x32_bf16(a, b, c, 0, 0, 0)

__device__ __forceinline__ unsigned short f2bf(float f) {
    return __builtin_bit_cast(unsigned short, (__bf16)f);
}

// 2^x via native v_exp_f32 (args bounded above by ~13; may be -1e18 -> 0)
__device__ __forceinline__ float fast_exp2(float x) {
#if __has_builtin(__builtin_amdgcn_exp2f)
    return __builtin_amdgcn_exp2f(x);
#else
    return exp2f(x);
#endif
}

// async global->LDS, 16B per lane; lds dest must be wave-uniform base + lane*16
__device__ __forceinline__ void gl_lds16(const unsigned short* g, unsigned short* l) {
    __builtin_amdgcn_global_load_lds(
        (const __attribute__((address_space(1))) void*)g,
        (__attribute__((address_space(3))) void*)l, 16, 0, 0);
}

// ---------------------------------------------------------------------------
// fp32 -> bf16 convert, 7 segments in one launch
// ---------------------------------------------------------------------------
struct CvtSeg { const float* s; unsigned short* d; int n; };
struct Cvt7 { CvtSeg seg[7]; };

__global__ __launch_bounds__(256) void cvt_kernel(Cvt7 a) {
    const CvtSeg c = a.seg[blockIdx.y];
    const int stride = gridDim.x * 256 * 4;
    for (int i = (blockIdx.x * 256 + threadIdx.x) * 4; i < c.n; i += stride) {
        float4v v = *(const float4v*)(c.s + i);
        ushort4v u;
        u.x = f2bf(v.x); u.y = f2bf(v.y); u.z = f2bf(v.z); u.w = f2bf(v.w);
        *(ushort4v*)(c.d + i) = u;
    }
}

// ---------------------------------------------------------------------------
// 128x128-tile GEMM (QKV projections): C = (A W^T + bias) * scale, bf16 out.
// ---------------------------------------------------------------------------
__device__ __forceinline__ void gemm128_body(const unsigned short* __restrict__ A,
                                             const unsigned short* __restrict__ W,
                                             const float* __restrict__ bias,
                                             unsigned short* __restrict__ Cout,
                                             int N, int K, float scale,
                                             unsigned short* As, unsigned short* Ws) {
    const int t = threadIdx.x;
    const int w = t >> 6, lane = t & 63;
    const int quad = lane >> 4, l16 = lane & 15;
    const int m0 = blockIdx.x * 128, n0 = blockIdx.y * 128;
    const int wm = (w >> 1) * 64, wn = (w & 1) * 64;

    float4v acc[4][4];
    for (int i = 0; i < 4; ++i)
        for (int j = 0; j < 4; ++j) acc[i][j] = float4v{0.f, 0.f, 0.f, 0.f};

    const int srow = lane >> 3;
    const int scol = (lane & 7) * 8;

    for (int k0 = 0; k0 < K; k0 += 64) {
        __syncthreads();
        for (int i = 0; i < 4; ++i) {
            const int c = w * 4 + i;
            gl_lds16(A + (size_t)(m0 + c * 8 + srow) * K + k0 + scol,
                     &As[c * 512 + lane * 8]);
            gl_lds16(W + (size_t)(n0 + c * 8 + srow) * K + k0 + scol,
                     &Ws[c * 512 + lane * 8]);
        }
        __syncthreads();
        for (int ks = 0; ks < 2; ++ks) {
            bf16x8 af[4], wf[4];
            for (int i = 0; i < 4; ++i)
                af[i] = *(const bf16x8*)&As[(wm + i * 16 + l16) * 64 + ks * 32 + quad * 8];
            for (int i = 0; i < 4; ++i)
                wf[i] = *(const bf16x8*)&Ws[(wn + i * 16 + l16) * 64 + ks * 32 + quad * 8];
            for (int mi = 0; mi < 4; ++mi)
                for (int ni = 0; ni < 4; ++ni)
                    acc[mi][ni] = MFMA16(af[mi], wf[ni], acc[mi][ni]);
        }
    }

    for (int mi = 0; mi < 4; ++mi)
        for (int ni = 0; ni < 4; ++ni) {
            const int col = n0 + wn + ni * 16 + l16;
            const float bv = bias[col];
            for (int reg = 0; reg < 4; ++reg) {
                const int row = m0 + wm + mi * 16 + quad * 4 + reg;
                Cout[(size_t)row * N + col] = f2bf((acc[mi][ni][reg] + bv) * scale);
            }
        }
}

__global__ __launch_bounds__(256) void gemm_qkv_kernel(
    const unsigned short* qa, const unsigned short* ka, const unsigned short* va,
    const unsigned short* Wqb, const unsigned short* Wkb, const unsigned short* Wvb,
    const float* bq, const float* bk, const float* bv,
    unsigned short* Qb, unsigned short* Kb, unsigned short* Vb, float qscale) {
    __shared__ unsigned short As[128 * 64];
    __shared__ unsigned short Ws[128 * 64];
    const int z = blockIdx.z;
    const unsigned short* A = z == 0 ? qa : (z == 1 ? ka : va);
    const unsigned short* W = z == 0 ? Wqb : (z == 1 ? Wkb : Wvb);
    const float* bias = z == 0 ? bq : (z == 1 ? bk : bv);
    unsigned short* C = z == 0 ? Qb : (z == 1 ? Kb : Vb);
    gemm128_body(A, W, bias, C, 1024, 1024, z == 0 ? qscale : 1.0f, As, Ws);
}

// ---------------------------------------------------------------------------
// 64x128-tile GEMM (output projection, fp32 out). 512 blocks = 2 blocks/CU.
// ---------------------------------------------------------------------------
__global__ __launch_bounds__(256) void gemm_out_kernel(const unsigned short* __restrict__ A,
                                                       const unsigned short* __restrict__ W,
                                                       const float* __restrict__ bias,
                                                       float* __restrict__ Cout) {
    __shared__ unsigned short As[64 * 64];
    __shared__ unsigned short Ws[128 * 64];
    const int N = 1024, K = 1024;
    const int t = threadIdx.x;
    const int w = t >> 6, lane = t & 63;
    const int quad = lane >> 4, l16 = lane & 15;
    const int m0 = blockIdx.x * 64, n0 = blockIdx.y * 128;
    const int wm = (w & 1) * 32, wn = (w >> 1) * 64;

    float4v acc[2][4];
    for (int i = 0; i < 2; ++i)
        for (int j = 0; j < 4; ++j) acc[i][j] = float4v{0.f, 0.f, 0.f, 0.f};

    const int srow = lane >> 3;
    const int scol = (lane & 7) * 8;

    for (int k0 = 0; k0 < K; k0 += 64) {
        __syncthreads();
        for (int i = 0; i < 2; ++i) {
            const int c = w * 2 + i;
            gl_lds16(A + (size_t)(m0 + c * 8 + srow) * K + k0 + scol,
                     &As[c * 512 + lane * 8]);
        }
        for (int i = 0; i < 4; ++i) {
            const int c = w * 4 + i;
            gl_lds16(W + (size_t)(n0 + c * 8 + srow) * K + k0 + scol,
                     &Ws[c * 512 + lane * 8]);
        }
        __syncthreads();
        for (int ks = 0; ks < 2; ++ks) {
            bf16x8 af[2], wf[4];
            for (int i = 0; i < 2; ++i)
                af[i] = *(const bf16x8*)&As[(wm + i * 16 + l16) * 64 + ks * 32 + quad * 8];
            for (int i = 0; i < 4; ++i)
                wf[i] = *(const bf16x8*)&Ws[(wn + i * 16 + l16) * 64 + ks * 32 + quad * 8];
            for (int mi = 0; mi < 2; ++mi)
                for (int ni = 0; ni < 4; ++ni)
                    acc[mi][ni] = MFMA16(af[mi], wf[ni], acc[mi][ni]);
        }
    }

    for (int mi = 0; mi < 2; ++mi)
        for (int ni = 0; ni < 4; ++ni) {
            const int col = n0 + wn + ni * 16 + l16;
            const float bv = bias[col];
            for (int reg = 0; reg < 4; ++reg) {
                const int row = m0 + wm + mi * 16 + quad * 4 + reg;
                Cout[(size_t)row * N + col] = acc[mi][ni][reg] + bv;
            }
        }
}

// ---------------------------------------------------------------------------
// Flash attention, S^T formulation, 128 q-rows/block (32 q per wave): each
// K/V fragment read now serves 2 q-groups, halving the dominant LDS terms.
// Lane packs 4 consecutive keys -> ds_write_b64 directly in A-layout Pt[q][k].
// l = per-lane scalar accumulators (q = l16 per group), shfl-reduced once.
// Grid: 512 blocks (bh fastest for XCD L2 locality).
// ---------------------------------------------------------------------------
__global__ __launch_bounds__(256) void attn_kernel(const unsigned short* __restrict__ Q,
                                                   const unsigned short* __restrict__ Kg,
                                                   const unsigned short* __restrict__ Vg,
                                                   const unsigned char* __restrict__ mask,
                                                   unsigned short* __restrict__ Ctx) {
    const int bid = blockIdx.x;
    const int bh = bid & 31;   // fastest -> same-XCD blocks share (b,h) K/V
    const int qt = bid >> 5;   // 0..15 (128-row q tile)
    const int b = bh >> 4, h = bh & 15;
    const int t = threadIdx.x, w = t >> 6, lane = t & 63;
    const int quad = lane >> 4, l16 = lane & 15;

    __shared__ unsigned short Pt[128][72];  // Q at start; then P in A-layout [q][key]
    __shared__ unsigned short Ks[64][72];
    __shared__ unsigned short Vt[64][72];   // transposed V: Vt[d][k]

    const unsigned short* Qp = Q + ((size_t)(b * 2048 + qt * 128)) * 1024 + h * 64;
    const unsigned short* Kp = Kg + ((size_t)b * 2048) * 1024 + h * 64;
    const unsigned short* Vp = Vg + ((size_t)b * 2048) * 1024 + h * 64;
    const unsigned char* Mp = mask + (size_t)(b * 2048 + qt * 128) * 2048;

    for (int p = 0; p < 4; ++p) {  // Q tile 128x64 -> Pt
        const int idx = t + p * 256;
        const int r = idx >> 3, c8 = (idx & 7) * 8;
        *(uint4*)&Pt[r][c8] = *(const uint4*)(Qp + (size_t)r * 1024 + c8);
    }
    __syncthreads();
    // qf[c] = B-operand fragment for q-group c (q = w*32 + c*16 + l16)
    bf16x8 qf[2][2];
    for (int c = 0; c < 2; ++c)
        for (int ks = 0; ks < 2; ++ks)
            qf[c][ks] = *(const bf16x8*)&Pt[w * 32 + c * 16 + l16][ks * 32 + quad * 8];

    float4v o[2][4];  // [q-chunk][d-tile]
    for (int c = 0; c < 2; ++c)
        for (int i = 0; i < 4; ++i) o[c][i] = float4v{0.f, 0.f, 0.f, 0.f};
    float l_acc[2] = {0.f, 0.f};  // per-lane partial row-sum for q-group c

    const int sr = t >> 3, sc8 = (t & 7) * 8;          // K staging map
    const int vkk = (t & 31) * 2, vd0 = (t >> 5) * 8;  // V staging map
    const int mrow = w * 32 + (lane >> 1);             // mask probe: 32 rows x 64 B
    const int mc0 = (lane & 1) * 32;

    uint4 kreg0, kreg1, vreg0, vreg1, mreg0, mreg1;
    {
        kreg0 = *(const uint4*)(Kp + (size_t)sr * 1024 + sc8);
        kreg1 = *(const uint4*)(Kp + (size_t)(sr + 32) * 1024 + sc8);
        vreg0 = *(const uint4*)(Vp + (size_t)vkk * 1024 + vd0);
        vreg1 = *(const uint4*)(Vp + (size_t)(vkk + 1) * 1024 + vd0);
        mreg0 = *(const uint4*)(Mp + (size_t)mrow * 2048 + mc0);
        mreg1 = *(const uint4*)(Mp + (size_t)mrow * 2048 + mc0 + 16);
    }

    for (int kc = 0; kc < 2048; kc += 64) {
        __syncthreads();  // prev iter's Ks/Vt readers done
        *(uint4*)&Ks[sr][sc8] = kreg0;
        *(uint4*)&Ks[sr + 32][sc8] = kreg1;
        {
            const unsigned short* pa = (const unsigned short*)&vreg0;
            const unsigned short* pb = (const unsigned short*)&vreg1;
            for (int j = 0; j < 8; ++j)
                *(unsigned int*)&Vt[vd0 + j][vkk] =
                    (unsigned int)pa[j] | ((unsigned int)pb[j] << 16);
        }
        const unsigned int mor = mreg0.x | mreg0.y | mreg0.z | mreg0.w |
                                 mreg1.x | mreg1.y | mreg1.z | mreg1.w;
        const bool anymask = __any(mor != 0);
        __syncthreads();  // staged data visible

        const int kn = kc + 64;
        if (kn < 2048) {  // prefetch next tile
            kreg0 = *(const uint4*)(Kp + (size_t)(kn + sr) * 1024 + sc8);
            kreg1 = *(const uint4*)(Kp + (size_t)(kn + sr + 32) * 1024 + sc8);
            vreg0 = *(const uint4*)(Vp + (size_t)(kn + vkk) * 1024 + vd0);
            vreg1 = *(const uint4*)(Vp + (size_t)(kn + vkk + 1) * 1024 + vd0);
            mreg0 = *(const uint4*)(Mp + (size_t)mrow * 2048 + kn + mc0);
            mreg1 = *(const uint4*)(Mp + (size_t)mrow * 2048 + kn + mc0 + 16);
        }

        // S^T = K Q^T for both q-groups; each kf read feeds 2 MFMAs
        float4v s0[4], s1[4];
        for (int nt = 0; nt < 4; ++nt) {
            const float4v z4 = float4v{0.f, 0.f, 0.f, 0.f};
            bf16x8 kf = *(const bf16x8*)&Ks[nt * 16 + l16][quad * 8];
            s0[nt] = MFMA16(kf, qf[0][0], z4);
            s1[nt] = MFMA16(kf, qf[1][0], z4);
            kf = *(const bf16x8*)&Ks[nt * 16 + l16][32 + quad * 8];
            s0[nt] = MFMA16(kf, qf[0][1], s0[nt]);
            s1[nt] = MFMA16(kf, qf[1][1], s1[nt]);
        }

        // exp2 + pack 4 consecutive keys -> one b64 store in A-layout
        for (int c = 0; c < 2; ++c) {
            float4v* s = c ? s1 : s0;
            const int qrow = w * 32 + c * 16 + l16;  // wave-private Pt row
            float lc = l_acc[c];
            for (int nt = 0; nt < 4; ++nt) {
                float p0 = s[nt][0], p1 = s[nt][1], p2 = s[nt][2], p3 = s[nt][3];
                if (anymask) {  // rare slow path: scalar byte re-read
                    const unsigned char* mr =
                        Mp + (size_t)qrow * 2048 + kc + nt * 16 + quad * 4;
                    if (mr[0]) p0 = -1e18f;
                    if (mr[1]) p1 = -1e18f;
                    if (mr[2]) p2 = -1e18f;
                    if (mr[3]) p3 = -1e18f;
                }
                const float e0 = fast_exp2(p0), e1 = fast_exp2(p1);
                const float e2 = fast_exp2(p2), e3 = fast_exp2(p3);
                lc += (e0 + e1) + (e2 + e3);
                uint2 u;
                u.x = (unsigned int)f2bf(e0) | ((unsigned int)f2bf(e1) << 16);
                u.y = (unsigned int)f2bf(e2) | ((unsigned int)f2bf(e3) << 16);
                *(uint2*)&Pt[qrow][nt * 16 + quad * 4] = u;
            }
            l_acc[c] = lc;
        }

        // O += P V ; each vf read feeds 2 MFMAs (both q-chunks)
        for (int ks = 0; ks < 2; ++ks) {
            bf16x8 pf0 = *(const bf16x8*)&Pt[w * 32 + l16][ks * 32 + quad * 8];
            bf16x8 pf1 = *(const bf16x8*)&Pt[w * 32 + 16 + l16][ks * 32 + quad * 8];
            for (int dt = 0; dt < 4; ++dt) {
                bf16x8 vf = *(const bf16x8*)&Vt[dt * 16 + l16][ks * 32 + quad * 8];
                o[0][dt] = MFMA16(pf0, vf, o[0][dt]);
                o[1][dt] = MFMA16(pf1, vf, o[1][dt]);
            }
        }
    }

    // reduce l over quads (uniform across quads after xor 16/32), per q-group
    float lfull[2];
    for (int c = 0; c < 2; ++c) {
        float l = l_acc[c];
        l += __shfl_xor(l, 16);
        l += __shfl_xor(l, 32);
        lfull[c] = l;
    }

    for (int c = 0; c < 2; ++c) {
        float inv[4];
        for (int reg = 0; reg < 4; ++reg)
            inv[reg] = 1.0f / __shfl(lfull[c], (lane & 48) | (quad * 4 + reg));
        for (int dt = 0; dt < 4; ++dt) {
            const int dcol = dt * 16 + l16;
            for (int reg = 0; reg < 4; ++reg) {
                const int ql = w * 32 + c * 16 + quad * 4 + reg;
                Ctx[((size_t)(b * 2048 + qt * 128 + ql)) * 1024 + h * 64 + dcol] =
                    f2bf(o[c][dt][reg] * inv[reg]);
            }
        }
    }
}

extern "C" void kernel_launch(void* const* d_in, const int* in_sizes, int n_in,
                              void* d_out, int out_size, void* d_ws, size_t ws_size,
                              hipStream_t stream) {
    (void)in_sizes; (void)n_in; (void)out_size; (void)ws_size;
    const float* query = (const float*)d_in[0];
    const float* key   = (const float*)d_in[1];
    const float* value = (const float*)d_in[2];
    const unsigned char* mask = (const unsigned char*)d_in[3];
    const float* Wq = (const float*)d_in[4];
    const float* bq = (const float*)d_in[5];
    const float* Wk = (const float*)d_in[6];
    const float* bk = (const float*)d_in[7];
    const float* Wv = (const float*)d_in[8];
    const float* bv = (const float*)d_in[9];
    const float* Wo = (const float*)d_in[10];
    const float* bo = (const float*)d_in[11];

    const size_t MD = (size_t)4096 * 1024;
    const size_t WD = (size_t)1024 * 1024;

    unsigned short* Qb  = (unsigned short*)d_ws;   // projected Q/K/V (bf16)
    unsigned short* Kb  = Qb + MD;
    unsigned short* Vb  = Kb + MD;
    unsigned short* qb  = Vb + MD;                 // bf16 inputs (dead after qkv)
    unsigned short* kb  = qb + MD;
    unsigned short* vb  = kb + MD;
    unsigned short* Wqb = vb + MD;
    unsigned short* Wkb = Wqb + WD;
    unsigned short* Wvb = Wkb + WD;
    unsigned short* Wob = Wvb + WD;
    unsigned short* Cb  = qb;                      // context aliases qb (dead by then)

    Cvt7 cv;
    cv.seg[0] = {query, qb, (int)MD};
    cv.seg[1] = {key,   kb, (int)MD};
    cv.seg[2] = {value, vb, (int)MD};
    cv.seg[3] = {Wq, Wqb, (int)WD};
    cv.seg[4] = {Wk, Wkb, (int)WD};
    cv.seg[5] = {Wv, Wvb, (int)WD};
    cv.seg[6] = {Wo, Wob, (int)WD};
    cvt_kernel<<<dim3(1024, 7), 256, 0, stream>>>(cv);

    // Q scale = (1/sqrt(64)) * log2(e); scores then live in log2 domain
    const float qscale = 0.125f * 1.44269504088896f;
    gemm_qkv_kernel<<<dim3(32, 8, 3), 256, 0, stream>>>(
        qb, kb, vb, Wqb, Wkb, Wvb, bq, bk, bv, Qb, Kb, Vb, qscale);

    attn_kernel<<<dim3(512), 256, 0, stream>>>(Qb, Kb, Vb, mask, Cb);

    gemm_out_kernel<<<dim3(64, 8), 256, 0, stream>>>(Cb, Wob, bo, (float*)d_out);
}